// Round 4
// baseline (199.599 us; speedup 1.0000x reference)
//
#include <hip/hip_runtime.h>

typedef float floatx4 __attribute__((ext_vector_type(4)));

// Fully-fused BNN: binarize(x) @ binarize(W)^T -> softsign -> binarize -> dot binarize(lin_w).
// Exact integer reformulation: with u = 2*xb in {0,1,2} = 2*uh + ul (uh: x>0.5, ul: x==0.5),
// v = 2*vb likewise, S = sum_k u*v = 4*Phh + 2*(Phl+Plh) + Pll (P** = popcounts of AND-ed
// 120-bit masks), y = S/4 exactly. binarize(softsign(y)) = (S>4 ? 1 : S==4 ? 0.5 : 0).
// Final dot folds the 0.5: store hlw = 0.5*binarize(lin_w) in {0,0.25,0.5}; then
//   fast path (no exact-0.5 anywhere): acc += min(p,2)  * hlw[c], p = popc(uh&vh)
//   slow path:                          acc += ((S>=4)+(S>4)) * hlw[c]
// Every product/sum lies on the exact quarter grid (< 2^24 quarters) -> bit-exact vs ref.
__global__ __launch_bounds__(256) void bnn_fused(
    const float* __restrict__ x, const float* __restrict__ w,
    const float* __restrict__ lin_w, float* __restrict__ out, int B)
{
    // LDS: [0..479] vh[c][4], [480..959] vl[c][4], [960..1079] hlw[c] (float bits),
    // [1081..1084] per-wave "w has exact 0.5" flags.
    __shared__ __attribute__((aligned(16))) unsigned int T[1088];

    const int tid = threadIdx.x;
    const long r  = (long)blockIdx.x * 256 + tid;
    const long rr = (r < B) ? r : (long)B - 1;

    // ---- issue first half of this thread's x-row (groups 0..14, 16B each) ----
    const floatx4* xr = (const floatx4*)(x + rr * 120);
    floatx4 buf[15];
    #pragma unroll
    for (int g = 0; g < 15; ++g) buf[g] = xr[g];

    // ---- build binarized-W bitmask table in LDS (2 threads per out-channel c;
    //      split at element 64 so the two halves own disjoint 32-bit words) ----
    unsigned int myvl = 0u;
    if (tid < 240) {
        const int c = tid >> 1, h = tid & 1;
        const floatx4* wr = (const floatx4*)(w + c * 120 + h * 64);
        unsigned int vh[2] = {0u, 0u}, vl[2] = {0u, 0u};
        const int ng = h ? 14 : 16;              // h=0: elems 0..63, h=1: elems 64..119
        #pragma unroll
        for (int g = 0; g < 16; ++g) {
            if (g < ng) {
                floatx4 f = wr[g];
                #pragma unroll
                for (int j = 0; j < 4; ++j) {
                    const int kl = 4 * g + j;    // local bit 0..63
                    const int wd = kl >> 5, sh = kl & 31;
                    float d = 0.5f - f[j];       // sign(d)=1 iff w>0.5; d==+0 iff w==0.5
                    unsigned int du = __float_as_uint(d);
                    vh[wd] |= (du >> 31) << sh;
                    vl[wd] |= (du == 0u) ? (1u << sh) : 0u;
                }
            }
        }
        T[c * 4 + 2 * h]           = vh[0];
        T[c * 4 + 2 * h + 1]       = vh[1];
        T[480 + c * 4 + 2 * h]     = vl[0];
        T[480 + c * 4 + 2 * h + 1] = vl[1];
        myvl = vl[0] | vl[1];
        if (h == 0) {
            float d = 0.5f - lin_w[c];
            unsigned int du = __float_as_uint(d);
            float hlw = (du >> 31) ? 0.5f : ((du == 0u) ? 0.25f : 0.0f);
            T[960 + c] = __float_as_uint(hlw);
        }
    }
    {   // per-wave OR of "w contains an exact 0.5" (no atomics, no init barrier)
        int wany = __any((int)(myvl != 0u));
        if ((tid & 63) == 0) T[1081 + (tid >> 6)] = (unsigned int)wany;
    }
    __syncthreads();

    // ---- issue second half of the x-row (groups 15..29) ----
    floatx4 buf2[15];
    #pragma unroll
    for (int g = 0; g < 15; ++g) buf2[g] = xr[15 + g];

    // ---- binarize x-row into 120-bit planes: uh (x>0.5), ul (x==0.5) ----
    unsigned int uh[4] = {0u,0u,0u,0u}, ul[4] = {0u,0u,0u,0u};
    #pragma unroll
    for (int g = 0; g < 15; ++g) {
        #pragma unroll
        for (int j = 0; j < 4; ++j) {
            const int k = 4 * g + j, wd = k >> 5, sh = k & 31;
            float d = 0.5f - buf[g][j];
            unsigned int du = __float_as_uint(d);
            uh[wd] |= (du >> 31) << sh;
            ul[wd] |= (du == 0u) ? (1u << sh) : 0u;
        }
    }
    #pragma unroll
    for (int g = 0; g < 15; ++g) {
        #pragma unroll
        for (int j = 0; j < 4; ++j) {
            const int k = 60 + 4 * g + j, wd = k >> 5, sh = k & 31;
            float d = 0.5f - buf2[g][j];
            unsigned int du = __float_as_uint(d);
            uh[wd] |= (du >> 31) << sh;
            ul[wd] |= (du == 0u) ? (1u << sh) : 0u;
        }
    }

    const unsigned int flagW = T[1081] | T[1082] | T[1083] | T[1084];
    const bool rare = ((ul[0] | ul[1] | ul[2] | ul[3]) != 0u) || (flagW != 0u);

    float acc = 0.0f;
    const float* hlwt = (const float*)&T[960];
    if (!__any((int)rare)) {
        // fast path: no exact 0.5 anywhere in this wave's rows nor in W
        #pragma unroll 4
        for (int c = 0; c < 120; ++c) {
            const uint4 v = *(const uint4*)&T[c * 4];   // broadcast ds_read_b128
            int p =  __popc(v.x & uh[0]);
            p    +=  __popc(v.y & uh[1]);
            p    +=  __popc(v.z & uh[2]);
            p    +=  __popc(v.w & uh[3]);
            acc = fmaf((float)min(p, 2), hlwt[c], acc);
        }
    } else {
        // exact slow path with half-planes (expected ~1 wave in 100k)
        #pragma unroll 2
        for (int c = 0; c < 120; ++c) {
            const uint4 a = *(const uint4*)&T[c * 4];
            const uint4 b = *(const uint4*)&T[480 + c * 4];
            int phh = __popc(a.x & uh[0]) + __popc(a.y & uh[1]) + __popc(a.z & uh[2]) + __popc(a.w & uh[3]);
            int phl = __popc(b.x & uh[0]) + __popc(b.y & uh[1]) + __popc(b.z & uh[2]) + __popc(b.w & uh[3]);
            int plh = __popc(a.x & ul[0]) + __popc(a.y & ul[1]) + __popc(a.z & ul[2]) + __popc(a.w & ul[3]);
            int pll = __popc(b.x & ul[0]) + __popc(b.y & ul[1]) + __popc(b.z & ul[2]) + __popc(b.w & ul[3]);
            int S = 4 * phh + 2 * (phl + plh) + pll;
            int t = (S >= 4 ? 1 : 0) + (S > 4 ? 1 : 0);
            acc = fmaf((float)t, hlwt[c], acc);
        }
    }
    if (r < B) out[r] = acc;
}

extern "C" void kernel_launch(void* const* d_in, const int* in_sizes, int n_in,
                              void* d_out, int out_size, void* d_ws, size_t ws_size,
                              hipStream_t stream) {
    const float* x      = (const float*)d_in[0];   // [B,1,1,120] fp32
    const float* conv_w = (const float*)d_in[1];   // [120,1,1,120] fp32
    const float* lin_w  = (const float*)d_in[2];   // [1,120] fp32
    float*       out    = (float*)d_out;           // [B,1] fp32

    const int B = in_sizes[0] / 120;
    const int blocks = (B + 255) / 256;
    bnn_fused<<<dim3(blocks), dim3(256), 0, stream>>>(x, conv_w, lin_w, out, B);
}

// Round 6
// 196.418 us; speedup vs baseline: 1.0162x; 1.0162x over previous
//
#include <hip/hip_runtime.h>

typedef float floatx4 __attribute__((ext_vector_type(4)));

// Fully-fused BNN, exact integer reformulation (see round-4 notes):
// y[b,c] = S/4 with S = 4*popc(uh&vh) + 2*(popc(uh&vl)+popc(ul&vh)) + popc(ul&vl),
// binarize(softsign(y)) = (S>4 ? 1 : S==4 ? 0.5 : 0); out = sum_c of that * lwb[c].
// Channel compaction: channels with binarize(lin_w)==0 contribute nothing -> drop
// (~half, lin_w~N(0.5,0.01)). Remaining grouped: G1 (hlw=0.5, vl==0), G2 (hlw=0.25,
// vl==0), G3 (vl!=0, stores vl+hlw). Fast path (row has no exact-0.5 x): ul=0 ->
// G1/G2: s += min(popc(uh&vh),2); G3: S=4p+2*popc(uh&vl). All terms stay on the
// exact quarter grid (sums < 2^24 quarters) -> bit-exact, order-independent.
//
// d_ws layout (uint32): [0]=n1 [1]=n2 [2]=n3 [3]=pad
//   [4..484)   V[120][4]   compacted vh quads (G1|G2|G3)
//   [484..964) VL3[120][4] vl quads (G3 only)
//   [964..1084) HL3[120]   hlw floats (G3 only)

__global__ __launch_bounds__(256) void bnn_prep(
    const float* __restrict__ w, const float* __restrict__ lin_w,
    unsigned int* __restrict__ ws)
{
    __shared__ unsigned int RH[120][4];
    __shared__ unsigned int RL[120][4];
    __shared__ float        HW[120];
    __shared__ unsigned int C[2][4];

    const int tid = threadIdx.x;
    // phase 1: 240 threads binarize half-channels (h=0: elems 0..63, h=1: 64..119)
    if (tid < 240) {
        const int c = tid >> 1, h = tid & 1;
        const floatx4* wr = (const floatx4*)(w + c * 120 + h * 64);
        unsigned int vh[2] = {0u, 0u}, vl[2] = {0u, 0u};
        const int ng = h ? 14 : 16;
        #pragma unroll
        for (int g = 0; g < 16; ++g) {
            if (g < ng) {
                floatx4 f = wr[g];
                #pragma unroll
                for (int j = 0; j < 4; ++j) {
                    const int kl = 4 * g + j, wd = kl >> 5, sh = kl & 31;
                    float d = 0.5f - f[j];          // sign=1 iff w>0.5; ==+0 iff w==0.5
                    unsigned int du = __float_as_uint(d);
                    vh[wd] |= (du >> 31) << sh;
                    vl[wd] |= (du == 0u) ? (1u << sh) : 0u;
                }
            }
        }
        RH[c][2 * h] = vh[0]; RH[c][2 * h + 1] = vh[1];
        RL[c][2 * h] = vl[0]; RL[c][2 * h + 1] = vl[1];
        if (h == 0) {
            float d = 0.5f - lin_w[c];
            unsigned int du = __float_as_uint(d);
            HW[c] = (du >> 31) ? 0.5f : ((du == 0u) ? 0.25f : 0.0f);
        }
    }
    __syncthreads();

    // phase 2: threads 0..127 classify + ballot-compact
    const int lane = tid & 63, wv = tid >> 6;
    int cls = 0;
    unsigned int vh4[4] = {0,0,0,0}, vl4[4] = {0,0,0,0};
    float hl = 0.f;
    if (tid < 120) {
        #pragma unroll
        for (int i = 0; i < 4; ++i) { vh4[i] = RH[tid][i]; vl4[i] = RL[tid][i]; }
        hl = HW[tid];
        const bool hasvl = (vl4[0] | vl4[1] | vl4[2] | vl4[3]) != 0u;
        if (hl != 0.f) cls = hasvl ? 3 : ((hl == 0.5f) ? 1 : 2);
    }
    unsigned long long b1 = 0, b2 = 0, b3 = 0;
    if (wv < 2) {
        b1 = __ballot(cls == 1); b2 = __ballot(cls == 2); b3 = __ballot(cls == 3);
        if (lane == 0) {
            C[wv][1] = (unsigned)__popcll(b1);
            C[wv][2] = (unsigned)__popcll(b2);
            C[wv][3] = (unsigned)__popcll(b3);
        }
    }
    __syncthreads();
    const int n1 = C[0][1] + C[1][1], n2 = C[0][2] + C[1][2], n3 = C[0][3] + C[1][3];
    if (tid == 0) { ws[0] = n1; ws[1] = n2; ws[2] = n3; ws[3] = 0u; }
    if (cls) {
        const unsigned long long lt = (((unsigned long long)1) << lane) - 1ull;
        uint4* V = (uint4*)(ws + 4);
        int idx, j = 0;
        if (cls == 1)      idx = (wv ? (int)C[0][1] : 0) + (int)__popcll(b1 & lt);
        else if (cls == 2) idx = n1 + (wv ? (int)C[0][2] : 0) + (int)__popcll(b2 & lt);
        else { j = (wv ? (int)C[0][3] : 0) + (int)__popcll(b3 & lt); idx = n1 + n2 + j; }
        V[idx] = make_uint4(vh4[0], vh4[1], vh4[2], vh4[3]);
        if (cls == 3) {
            ((uint4*)(ws + 484))[j] = make_uint4(vl4[0], vl4[1], vl4[2], vl4[3]);
            ((float*)ws)[964 + j] = hl;
        }
    }
}

__device__ __forceinline__ int popc4(uint4 v, unsigned a, unsigned b, unsigned c, unsigned d) {
    return __popc(v.x & a) + __popc(v.y & b) + __popc(v.z & c) + __popc(v.w & d);
}

__global__ __launch_bounds__(256, 4) void bnn_main(
    const float* __restrict__ x, const unsigned int* __restrict__ ws,
    float* __restrict__ out, int B)
{
    __shared__ __attribute__((aligned(16))) unsigned int T[1088];
    const int tid = threadIdx.x;
    const long r  = (long)blockIdx.x * 256 + tid;
    const long rr = (r < B) ? r : (long)B - 1;
    const floatx4* xr = (const floatx4*)(x + rr * 120);

    // batch A of this row (elems 0..59) — issue early
    floatx4 bufA[15];
    #pragma unroll
    for (int g = 0; g < 15; ++g) bufA[g] = xr[g];

    // stage compact table global->LDS (4352 B)
    {
        const uint4* g4 = (const uint4*)ws;
        uint4* t4 = (uint4*)T;
        t4[tid] = g4[tid];
        if (tid < 16) t4[256 + tid] = g4[256 + tid];
    }

    // batch B (elems 60..119)
    floatx4 bufB[15];
    #pragma unroll
    for (int g = 0; g < 15; ++g) bufB[g] = xr[15 + g];

    // binarize: uh bit k = (x_k > 0.5); mn==0 detects any exact 0.5 (Sterbenz-exact)
    unsigned uh0 = 0, uh1 = 0, uh2 = 0, uh3 = 0, mn = 0xFFFFFFFFu;
    #pragma unroll
    for (int g = 0; g < 15; ++g) {
        #pragma unroll
        for (int j = 0; j < 4; ++j) {
            const int k = 4 * g + j;
            unsigned du = __float_as_uint(0.5f - bufA[g][j]);
            mn = min(mn, du);
            unsigned bit = du >> 31;
            if (k < 32) uh0 |= bit << k; else uh1 |= bit << (k - 32);
        }
    }
    __syncthreads();
    #pragma unroll
    for (int g = 0; g < 15; ++g) {
        #pragma unroll
        for (int j = 0; j < 4; ++j) {
            const int k = 60 + 4 * g + j;
            unsigned du = __float_as_uint(0.5f - bufB[g][j]);
            mn = min(mn, du);
            unsigned bit = du >> 31;
            if (k < 64)      uh1 |= bit << (k - 32);
            else if (k < 96) uh2 |= bit << (k - 64);
            else             uh3 |= bit << (k - 96);
        }
    }

    const int n1 = (int)T[0], n2 = (int)T[1], n3 = (int)T[2];
    const uint4* V  = (const uint4*)&T[4];
    const uint4* VL = (const uint4*)&T[484];
    const float* HL = (const float*)&T[964];

    float acc;
    if (!__any((int)(mn == 0u))) {
        // fast path: no exact-0.5 x in this wave's rows -> ul = 0
        int s1 = 0;
        #pragma unroll 4
        for (int c = 0; c < n1; ++c) {
            int p = popc4(V[c], uh0, uh1, uh2, uh3);
            s1 += (p < 2 ? p : 2);
        }
        int s2 = 0;
        for (int c = n1; c < n1 + n2; ++c) {
            int p = popc4(V[c], uh0, uh1, uh2, uh3);
            s2 += (p < 2 ? p : 2);
        }
        acc = fmaf((float)s1, 0.5f, 0.25f * (float)s2);
        for (int j = 0; j < n3; ++j) {
            int p = popc4(V[n1 + n2 + j], uh0, uh1, uh2, uh3);
            int q = popc4(VL[j], uh0, uh1, uh2, uh3);
            int S = 4 * p + 2 * q;
            int t = (S >= 4 ? 1 : 0) + (S > 4 ? 1 : 0);
            acc = fmaf((float)t, HL[j], acc);
        }
    } else {
        // rare exact path: rebuild ul plane (reload row; L2-hot)
        unsigned ul0 = 0, ul1 = 0, ul2 = 0, ul3 = 0;
        for (int g = 0; g < 30; ++g) {
            floatx4 f = xr[g];
            #pragma unroll
            for (int j = 0; j < 4; ++j) {
                const int k = 4 * g + j;
                unsigned du = __float_as_uint(0.5f - f[j]);
                unsigned e = (du == 0u) ? 1u : 0u;
                if (k < 32)      ul0 |= e << k;
                else if (k < 64) ul1 |= e << (k - 32);
                else if (k < 96) ul2 |= e << (k - 64);
                else             ul3 |= e << (k - 96);
            }
        }
        int s1 = 0, s2 = 0;
        for (int c = 0; c < n1 + n2; ++c) {
            uint4 v = V[c];
            int S = 4 * popc4(v, uh0, uh1, uh2, uh3) + 2 * popc4(v, ul0, ul1, ul2, ul3);
            int t = (S >= 4 ? 1 : 0) + (S > 4 ? 1 : 0);
            if (c < n1) s1 += t; else s2 += t;
        }
        acc = fmaf((float)s1, 0.5f, 0.25f * (float)s2);
        for (int j = 0; j < n3; ++j) {
            uint4 v = V[n1 + n2 + j], l = VL[j];
            int S = 4 * popc4(v, uh0, uh1, uh2, uh3)
                  + 2 * (popc4(l, uh0, uh1, uh2, uh3) + popc4(v, ul0, ul1, ul2, ul3))
                  + popc4(l, ul0, ul1, ul2, ul3);
            int t = (S >= 4 ? 1 : 0) + (S > 4 ? 1 : 0);
            acc = fmaf((float)t, HL[j], acc);
        }
    }
    if (r < B) out[r] = acc;
}

extern "C" void kernel_launch(void* const* d_in, const int* in_sizes, int n_in,
                              void* d_out, int out_size, void* d_ws, size_t ws_size,
                              hipStream_t stream) {
    const float* x      = (const float*)d_in[0];   // [B,1,1,120] fp32
    const float* conv_w = (const float*)d_in[1];   // [120,1,1,120] fp32
    const float* lin_w  = (const float*)d_in[2];   // [1,120] fp32
    float*       out    = (float*)d_out;           // [B,1] fp32
    unsigned int* ws    = (unsigned int*)d_ws;

    bnn_prep<<<dim3(1), dim3(256), 0, stream>>>(conv_w, lin_w, ws);

    const int B = in_sizes[0] / 120;
    const int blocks = (B + 255) / 256;
    bnn_main<<<dim3(blocks), dim3(256), 0, stream>>>(x, ws, out, B);
}